// Round 2
// baseline (220.810 us; speedup 1.0000x reference)
//
#include <hip/hip_runtime.h>

#define TT 256
#define SS 5
#define DD 32
#define NT 4

__device__ __forceinline__ float frcp(float v) { return __builtin_amdgcn_rcpf(v); }

__global__ void __launch_bounds__(256, 4)
mem_net_kernel(const float* __restrict__ x,
               const float* __restrict__ q,
               const float* __restrict__ keys,
               const float* __restrict__ Wu,
               const float* __restrict__ bu,
               const int*   __restrict__ lens,
               const int*   __restrict__ labels,
               const int*   __restrict__ qlab,
               float*       __restrict__ out)
{
    // keys: [lab][s][36]: lab stride 180 floats -> banks {0,20,8,28}, s stride 36 (16B aligned)
    __shared__ __align__(16) float kS[NT][SS][36];
    __shared__ float wTot[4][SS];
    __shared__ float rS[8];
    __shared__ __align__(16) float red[4][DD];

    const int b    = blockIdx.x;
    const int tid  = threadIdx.x;
    const int lane = tid & 63;
    const int w    = tid >> 6;
    const int len  = lens[b];
    const int ql   = qlab[b];
    const int t    = tid;
    const bool valid = (t < len);

    // ---- stage keys (640 floats, tiny) ----
    for (int i = tid; i < NT * SS * DD; i += 256) {
        const int ty = i / (SS * DD);
        const int s  = (i / DD) % SS;
        const int d  = i & (DD - 1);
        kS[ty][s][d] = keys[i];
    }

    // ---- x row t -> registers (skip invalid rows: halves HBM reads) ----
    float4 xr[8];
    #pragma unroll
    for (int j = 0; j < 8; ++j) xr[j] = make_float4(0.f, 0.f, 0.f, 0.f);
    if (valid) {
        const float4* xrow = reinterpret_cast<const float4*>(x + ((size_t)b * TT + t) * DD);
        #pragma unroll
        for (int j = 0; j < 8; ++j) xr[j] = xrow[j];
    }

    __syncthreads();

    // ---- phase B: a_t[s] = softmax_s(x_t . keys[lab][s]) ----
    float a[SS];
    #pragma unroll
    for (int s = 0; s < SS; ++s) a[s] = 0.f;
    if (valid) {
        const int lab = (t < len - 1) ? labels[(size_t)b * TT + t] : 0;
        float z[SS];
        #pragma unroll
        for (int s = 0; s < SS; ++s) {
            const float4* kp = reinterpret_cast<const float4*>(&kS[lab][s][0]);
            float acc = 0.f;
            #pragma unroll
            for (int j = 0; j < 8; ++j) {
                const float4 kv = kp[j];
                acc += xr[j].x * kv.x + xr[j].y * kv.y + xr[j].z * kv.z + xr[j].w * kv.w;
            }
            z[s] = acc;
        }
        float m = z[0];
        #pragma unroll
        for (int s = 1; s < SS; ++s) m = fmaxf(m, z[s]);
        float e[SS];
        float sum = 0.f;
        #pragma unroll
        for (int s = 0; s < SS; ++s) { e[s] = __expf(z[s] - m); sum += e[s]; }
        const float inv = frcp(sum);
        #pragma unroll
        for (int s = 0; s < SS; ++s) a[s] = e[s] * inv;
    }

    // ---- phase C: suffix-product scan over t (in-register, per s) ----
    float excl[SS];
    #pragma unroll
    for (int s = 0; s < SS; ++s) {
        float p = 1.f - a[s];                      // = 1 for invalid t (a=0)
        #pragma unroll
        for (int off = 1; off < 64; off <<= 1) {   // intra-wave inclusive suffix product
            const float o = __shfl_down(p, off);
            p = (lane + off < 64) ? p * o : p;
        }
        float e = __shfl_down(p, 1);               // exclusive suffix within wave
        if (lane == 63) e = 1.f;
        excl[s] = e;
        if (lane == 0) wTot[w][s] = p;             // wave total product
    }

    // wave 0 also computes r_attn = softmax_s(q . keys[ql][s])
    if (w == 0) {
        const int d = lane & (DD - 1);
        const float qv = q[(size_t)b * DD + d];
        float p[SS];
        #pragma unroll
        for (int s = 0; s < SS; ++s) p[s] = qv * kS[ql][s][d];
        #pragma unroll
        for (int m = 16; m >= 1; m >>= 1) {
            #pragma unroll
            for (int s = 0; s < SS; ++s) p[s] += __shfl_xor(p[s], m);
        }
        float mm = p[0];
        #pragma unroll
        for (int s = 1; s < SS; ++s) mm = fmaxf(mm, p[s]);
        float e[SS];
        float sum = 0.f;
        #pragma unroll
        for (int s = 0; s < SS; ++s) { e[s] = __expf(p[s] - mm); sum += e[s]; }
        const float inv = frcp(sum);
        if (lane == 0) {
            #pragma unroll
            for (int s = 0; s < SS; ++s) rS[s] = e[s] * inv;
        }
    }
    __syncthreads();

    // combine with cross-wave suffix, fold in r_attn -> scalar weight c_t
    float c = 0.f;
    #pragma unroll
    for (int s = 0; s < SS; ++s) {
        float wsuf = 1.f;
        if (w <= 2) wsuf *= wTot[3][s];
        if (w <= 1) wsuf *= wTot[2][s];
        if (w == 0) wsuf *= wTot[1][s];
        c += rS[s] * (a[s] * excl[s] * wsuf);
    }

    // ---- phase D: y = c * sigmoid(x_t @ Wu + bu); Wu/bu via uniform s_loads ----
    float y[DD];
    if (valid) {
        #pragma unroll
        for (int n = 0; n < DD; ++n) y[n] = bu[n];
        #pragma unroll
        for (int k4 = 0; k4 < 8; ++k4) {
            const float* W0 = Wu + (k4 * 4 + 0) * DD;
            const float* W1 = Wu + (k4 * 4 + 1) * DD;
            const float* W2 = Wu + (k4 * 4 + 2) * DD;
            const float* W3 = Wu + (k4 * 4 + 3) * DD;
            #pragma unroll
            for (int n = 0; n < DD; ++n)
                y[n] += xr[k4].x * W0[n] + xr[k4].y * W1[n]
                      + xr[k4].z * W2[n] + xr[k4].w * W3[n];
        }
        #pragma unroll
        for (int n = 0; n < DD; ++n)
            y[n] = c * frcp(1.f + __expf(-y[n]));
    } else {
        #pragma unroll
        for (int n = 0; n < DD; ++n) y[n] = 0.f;
    }

    // ---- value-splitting butterfly: 32 values x 64 lanes -> 1 value/lane ----
    // After 5 stages lane holds d=(lane>>1)&31 summed over lanes of same parity;
    // final xor-1 completes the 64-lane sum.
    {
        #pragma unroll
        for (int i = 0; i < 16; ++i) {
            const bool hi = (lane & 32) != 0;
            const float send = hi ? y[i] : y[i + 16];
            const float keep = hi ? y[i + 16] : y[i];
            y[i] = keep + __shfl_xor(send, 32);
        }
        #pragma unroll
        for (int i = 0; i < 8; ++i) {
            const bool hi = (lane & 16) != 0;
            const float send = hi ? y[i] : y[i + 8];
            const float keep = hi ? y[i + 8] : y[i];
            y[i] = keep + __shfl_xor(send, 16);
        }
        #pragma unroll
        for (int i = 0; i < 4; ++i) {
            const bool hi = (lane & 8) != 0;
            const float send = hi ? y[i] : y[i + 4];
            const float keep = hi ? y[i + 4] : y[i];
            y[i] = keep + __shfl_xor(send, 8);
        }
        #pragma unroll
        for (int i = 0; i < 2; ++i) {
            const bool hi = (lane & 4) != 0;
            const float send = hi ? y[i] : y[i + 2];
            const float keep = hi ? y[i + 2] : y[i];
            y[i] = keep + __shfl_xor(send, 4);
        }
        {
            const bool hi = (lane & 2) != 0;
            const float send = hi ? y[0] : y[1];
            const float keep = hi ? y[1] : y[0];
            y[0] = keep + __shfl_xor(send, 2);
        }
        y[0] += __shfl_xor(y[0], 1);
    }
    if ((lane & 1) == 0) red[w][lane >> 1] = y[0];
    __syncthreads();

    if (tid < DD) {
        out[(size_t)b * DD + tid] = red[0][tid] + red[1][tid] + red[2][tid] + red[3][tid];
    }
}

extern "C" void kernel_launch(void* const* d_in, const int* in_sizes, int n_in,
                              void* d_out, int out_size, void* d_ws, size_t ws_size,
                              hipStream_t stream) {
    const float* x      = (const float*)d_in[0];
    const float* q      = (const float*)d_in[1];
    const float* keys   = (const float*)d_in[2];
    const float* Wu     = (const float*)d_in[3];
    const float* bu     = (const float*)d_in[4];
    const int*   lens   = (const int*)d_in[5];
    const int*   labels = (const int*)d_in[6];
    const int*   qlab   = (const int*)d_in[7];
    float* out = (float*)d_out;

    hipLaunchKernelGGL(mem_net_kernel, dim3(4096), dim3(256), 0, stream,
                       x, q, keys, Wu, bu, lens, labels, qlab, out);
}

// Round 3
// 34.574 us; speedup vs baseline: 6.3866x; 6.3866x over previous
//
#include <hip/hip_runtime.h>

typedef __attribute__((ext_vector_type(8))) short bf16x8;
typedef __attribute__((ext_vector_type(4))) float f32x4;

#define TT 256
#define SS 5
#define DD 32
#define NT 4

__device__ __forceinline__ float frcp(float v) { return __builtin_amdgcn_rcpf(v); }

// round-to-nearest-even fp32 -> bf16, two values packed into one dword
__device__ __forceinline__ unsigned f2bf2(float lo, float hi) {
    unsigned a = __float_as_uint(lo), b = __float_as_uint(hi);
    a = (a + 0x7fffu + ((a >> 16) & 1u)) >> 16;
    b = (b + 0x7fffu + ((b >> 16) & 1u)) & 0xffff0000u;
    return a | b;
}

union F8 { unsigned u[4]; bf16x8 v; };

__global__ void __launch_bounds__(256, 4)
mem_net_kernel(const float* __restrict__ x,
               const float* __restrict__ q,
               const float* __restrict__ keys,
               const float* __restrict__ Wu,
               const float* __restrict__ bu,
               const int*   __restrict__ lens,
               const int*   __restrict__ labels,
               const int*   __restrict__ qlab,
               float*       __restrict__ out)
{
    __shared__ __align__(16) float kS[NT][SS][36];  // lab stride 180f -> banks {0,20,8,28}
    __shared__ float wTot[4][SS];
    __shared__ float rS[8];
    __shared__ __align__(16) float cS[TT];
    __shared__ __align__(16) float red[4][DD];

    const int b    = blockIdx.x;
    const int tid  = threadIdx.x;
    const int l    = tid & 63;
    const int w    = tid >> 6;
    const int len  = lens[b];
    const int ql   = qlab[b];
    const int t    = tid;
    const bool valid   = (t < len);
    const bool wactive = ((w << 6) < len);

    // ---- stage keys (640 floats) ----
    for (int i = tid; i < NT * SS * DD; i += 256) {
        const int ty = i / (SS * DD);
        const int s  = (i / DD) % SS;
        const int d  = i & (DD - 1);
        kS[ty][s][d] = keys[i];
    }

    // ---- x row t -> registers (valid rows only) ----
    float4 xr[8];
    #pragma unroll
    for (int j = 0; j < 8; ++j) xr[j] = make_float4(0.f, 0.f, 0.f, 0.f);
    if (valid) {
        const float4* xrow = reinterpret_cast<const float4*>(x + ((size_t)b * TT + t) * DD);
        #pragma unroll
        for (int j = 0; j < 8; ++j) xr[j] = xrow[j];
    }

    __syncthreads();

    // ---- phase B: a_t[s] = softmax_s(x_t . keys[lab][s]) ----
    float a[SS];
    #pragma unroll
    for (int s = 0; s < SS; ++s) a[s] = 0.f;
    if (valid) {
        const int lab = (t < len - 1) ? labels[(size_t)b * TT + t] : 0;
        float z[SS];
        #pragma unroll
        for (int s = 0; s < SS; ++s) {
            const float4* kp = reinterpret_cast<const float4*>(&kS[lab][s][0]);
            float acc = 0.f;
            #pragma unroll
            for (int j = 0; j < 8; ++j) {
                const float4 kv = kp[j];
                acc += xr[j].x * kv.x + xr[j].y * kv.y + xr[j].z * kv.z + xr[j].w * kv.w;
            }
            z[s] = acc;
        }
        float m = z[0];
        #pragma unroll
        for (int s = 1; s < SS; ++s) m = fmaxf(m, z[s]);
        float e[SS];
        float sum = 0.f;
        #pragma unroll
        for (int s = 0; s < SS; ++s) { e[s] = __expf(z[s] - m); sum += e[s]; }
        const float inv = frcp(sum);
        #pragma unroll
        for (int s = 0; s < SS; ++s) a[s] = e[s] * inv;
    }

    // ---- phase C: suffix-product scan (skip fully-inactive waves) ----
    float excl[SS];
    if (wactive) {
        #pragma unroll
        for (int s = 0; s < SS; ++s) {
            float p = 1.f - a[s];
            #pragma unroll
            for (int off = 1; off < 64; off <<= 1) {
                const float o = __shfl_down(p, off);
                p = (l + off < 64) ? p * o : p;
            }
            float e = __shfl_down(p, 1);
            if (l == 63) e = 1.f;
            excl[s] = e;
            if (l == 0) wTot[w][s] = p;
        }
    } else {
        #pragma unroll
        for (int s = 0; s < SS; ++s) excl[s] = 1.f;
        if (l == 0) {
            #pragma unroll
            for (int s = 0; s < SS; ++s) wTot[w][s] = 1.f;
        }
    }

    // wave 0: r_attn = softmax_s(q . keys[ql][s])  (always, len-independent)
    if (w == 0) {
        const int d = l & (DD - 1);
        const float qv = q[(size_t)b * DD + d];
        float p[SS];
        #pragma unroll
        for (int s = 0; s < SS; ++s) p[s] = qv * kS[ql][s][d];
        #pragma unroll
        for (int m = 16; m >= 1; m >>= 1) {
            #pragma unroll
            for (int s = 0; s < SS; ++s) p[s] += __shfl_xor(p[s], m);
        }
        float mm = p[0];
        #pragma unroll
        for (int s = 1; s < SS; ++s) mm = fmaxf(mm, p[s]);
        float e[SS];
        float sum = 0.f;
        #pragma unroll
        for (int s = 0; s < SS; ++s) { e[s] = __expf(p[s] - mm); sum += e[s]; }
        const float inv = frcp(sum);
        if (l == 0) {
            #pragma unroll
            for (int s = 0; s < SS; ++s) rS[s] = e[s] * inv;
        }
    }
    __syncthreads();

    // ---- per-row scalar weight c_t -> LDS ----
    float c = 0.f;
    if (valid) {
        #pragma unroll
        for (int s = 0; s < SS; ++s) {
            float wsuf = 1.f;
            if (w <= 2) wsuf *= wTot[3][s];
            if (w <= 1) wsuf *= wTot[2][s];
            if (w == 0) wsuf *= wTot[1][s];
            c += rS[s] * (a[s] * excl[s] * wsuf);
        }
    }
    cS[t] = c;
    __syncthreads();

    // ---- phase D: MFMA  U = sigmoid(X @ Wu + bu);  p = sum_t c_t * U_t ----
    float p0 = 0.f, p1 = 0.f;
    {
        const int n0 = l & 15;
        const int kb = (l >> 4) << 3;           // k-chunk base: 0,8,16,24
        if (wactive) {
            // B fragments (Wu cols n0 and n0+16), bf16, built once
            F8 bw0, bw1;
            #pragma unroll
            for (int j = 0; j < 4; ++j) {
                const int k0 = kb + 2 * j;
                bw0.u[j] = f2bf2(Wu[k0 * DD + n0],      Wu[(k0 + 1) * DD + n0]);
                bw1.u[j] = f2bf2(Wu[k0 * DD + n0 + 16], Wu[(k0 + 1) * DD + n0 + 16]);
            }
            const float bub0 = bu[n0], bub1 = bu[n0 + 16];

            #pragma unroll
            for (int rt = 0; rt < 4; ++rt) {
                const int rbase = (w << 6) + (rt << 4);     // tile's first row
                if (rbase < len) {                           // wave-uniform
                    // A fragment straight from global x (L1/L2-hot)
                    const float* xt = x + ((size_t)b * TT + rbase + n0) * DD + kb;
                    const float4 f0 = *reinterpret_cast<const float4*>(xt);
                    const float4 f1 = *reinterpret_cast<const float4*>(xt + 4);
                    F8 af;
                    af.u[0] = f2bf2(f0.x, f0.y); af.u[1] = f2bf2(f0.z, f0.w);
                    af.u[2] = f2bf2(f1.x, f1.y); af.u[3] = f2bf2(f1.z, f1.w);

                    f32x4 acc0 = {0.f, 0.f, 0.f, 0.f};
                    f32x4 acc1 = {0.f, 0.f, 0.f, 0.f};
                    acc0 = __builtin_amdgcn_mfma_f32_16x16x32_bf16(af.v, bw0.v, acc0, 0, 0, 0);
                    acc1 = __builtin_amdgcn_mfma_f32_16x16x32_bf16(af.v, bw1.v, acc1, 0, 0, 0);

                    const float4 cf = *reinterpret_cast<const float4*>(&cS[rbase + ((l >> 4) << 2)]);
                    const float cfa[4] = {cf.x, cf.y, cf.z, cf.w};
                    #pragma unroll
                    for (int r = 0; r < 4; ++r) {
                        p0 += cfa[r] * frcp(1.f + __expf(-(acc0[r] + bub0)));
                        p1 += cfa[r] * frcp(1.f + __expf(-(acc1[r] + bub1)));
                    }
                }
            }
        }
    }
    p0 += __shfl_xor(p0, 16); p0 += __shfl_xor(p0, 32);
    p1 += __shfl_xor(p1, 16); p1 += __shfl_xor(p1, 32);
    if (l < 16) { red[w][l] = p0; red[w][l + 16] = p1; }
    __syncthreads();

    if (tid < DD) {
        out[(size_t)b * DD + tid] = red[0][tid] + red[1][tid] + red[2][tid] + red[3][tid];
    }
}

extern "C" void kernel_launch(void* const* d_in, const int* in_sizes, int n_in,
                              void* d_out, int out_size, void* d_ws, size_t ws_size,
                              hipStream_t stream) {
    const float* x      = (const float*)d_in[0];
    const float* q      = (const float*)d_in[1];
    const float* keys   = (const float*)d_in[2];
    const float* Wu     = (const float*)d_in[3];
    const float* bu     = (const float*)d_in[4];
    const int*   lens   = (const int*)d_in[5];
    const int*   labels = (const int*)d_in[6];
    const int*   qlab   = (const int*)d_in[7];
    float* out = (float*)d_out;

    hipLaunchKernelGGL(mem_net_kernel, dim3(4096), dim3(256), 0, stream,
                       x, q, keys, Wu, bu, lens, labels, qlab, out);
}

// Round 4
// 33.670 us; speedup vs baseline: 6.5582x; 1.0269x over previous
//
#include <hip/hip_runtime.h>

typedef __attribute__((ext_vector_type(8))) short bf16x8;
typedef __attribute__((ext_vector_type(4))) float f32x4;

#define TT 256
#define SS 5
#define DD 32
#define NT 4
#define ZP 21   // zS row stride: gcd(21,32)=1 -> conflict-light

__device__ __forceinline__ float frcp(float v) { return __builtin_amdgcn_rcpf(v); }

// pack two fp32 -> two bf16 (RNE) in one dword (first arg in low half)
__device__ __forceinline__ unsigned f2bf2(float lo, float hi) {
    unsigned a = __float_as_uint(lo), b = __float_as_uint(hi);
    a = (a + 0x7fffu + ((a >> 16) & 1u)) >> 16;
    b = (b + 0x7fffu + ((b >> 16) & 1u)) & 0xffff0000u;
    return a | b;
}
// RNE-rounded bf16 value, kept as fp32
__device__ __forceinline__ float bfhi(float v) {
    unsigned a = __float_as_uint(v);
    a = (a + 0x7fffu + ((a >> 16) & 1u)) & 0xffff0000u;
    return __uint_as_float(a);
}

union F8 { unsigned u[4]; bf16x8 v; };

// split 8 fp32 into hi/lo bf16 fragments (Markidis split)
__device__ __forceinline__ void split8(const float4 f0, const float4 f1, F8& h, F8& lo) {
    const float f[8] = {f0.x, f0.y, f0.z, f0.w, f1.x, f1.y, f1.z, f1.w};
    float hv[8], lv[8];
    #pragma unroll
    for (int j = 0; j < 8; ++j) { hv[j] = bfhi(f[j]); lv[j] = f[j] - hv[j]; }
    #pragma unroll
    for (int j = 0; j < 4; ++j) {
        h.u[j]  = (__float_as_uint(hv[2*j]) >> 16) | (__float_as_uint(hv[2*j+1]) & 0xffff0000u);
        lo.u[j] = f2bf2(lv[2*j], lv[2*j+1]);
    }
}

__global__ void __launch_bounds__(256, 4)
mem_net_kernel(const float* __restrict__ x,
               const float* __restrict__ q,
               const float* __restrict__ keys,
               const float* __restrict__ Wu,
               const float* __restrict__ bu,
               const int*   __restrict__ lens,
               const int*   __restrict__ labels,
               const int*   __restrict__ qlab,
               float*       __restrict__ out)
{
    __shared__ __align__(16) float zS[TT][ZP];   // QK logits, all 20 cols
    __shared__ float wTot[4][SS];
    __shared__ float rS[8];
    __shared__ __align__(16) float cS[TT];
    __shared__ __align__(16) float red[4][DD];

    const int b    = blockIdx.x;
    const int tid  = threadIdx.x;
    const int l    = tid & 63;
    const int w    = tid >> 6;
    const int len  = lens[b];
    const int ql   = qlab[b];
    const int t    = tid;
    const bool valid   = (t < len);
    const bool wactive = ((w << 6) < len);

    const int n0 = l & 15;           // fragment col/row lane index
    const int kb = (l >> 4) << 3;    // k-chunk base: 0,8,16,24

    // ---- K_all^T B-fragments, hi/lo (keys: [20][32], cols >=20 zero) ----
    F8 kh0, kl0, kh1, kl1;
    F8 xh[4], xl[4];
    if (wactive) {
        {
            const float* kp = keys + (size_t)n0 * DD + kb;
            const float4 g0 = *reinterpret_cast<const float4*>(kp);
            const float4 g1 = *reinterpret_cast<const float4*>(kp + 4);
            split8(g0, g1, kh0, kl0);
            if (n0 < 4) {
                const float* kp1 = keys + (size_t)(16 + n0) * DD + kb;
                const float4 h0 = *reinterpret_cast<const float4*>(kp1);
                const float4 h1 = *reinterpret_cast<const float4*>(kp1 + 4);
                split8(h0, h1, kh1, kl1);
            } else {
                #pragma unroll
                for (int j = 0; j < 4; ++j) { kh1.u[j] = 0u; kl1.u[j] = 0u; }
            }
        }

        // ---- per row-tile: load x once (hi/lo), 6 MFMAs, scatter Z to LDS ----
        #pragma unroll
        for (int rt = 0; rt < 4; ++rt) {
            const int rbase = (w << 6) + (rt << 4);
            if (rbase < len) {                          // wave-uniform
                const float* xt = x + ((size_t)b * TT + rbase + n0) * DD + kb;
                const float4 f0 = *reinterpret_cast<const float4*>(xt);
                const float4 f1 = *reinterpret_cast<const float4*>(xt + 4);
                split8(f0, f1, xh[rt], xl[rt]);

                f32x4 z0 = {0.f, 0.f, 0.f, 0.f};
                f32x4 z1 = {0.f, 0.f, 0.f, 0.f};
                z0 = __builtin_amdgcn_mfma_f32_16x16x32_bf16(xl[rt].v, kh0.v, z0, 0, 0, 0);
                z0 = __builtin_amdgcn_mfma_f32_16x16x32_bf16(xh[rt].v, kl0.v, z0, 0, 0, 0);
                z0 = __builtin_amdgcn_mfma_f32_16x16x32_bf16(xh[rt].v, kh0.v, z0, 0, 0, 0);
                z1 = __builtin_amdgcn_mfma_f32_16x16x32_bf16(xl[rt].v, kh1.v, z1, 0, 0, 0);
                z1 = __builtin_amdgcn_mfma_f32_16x16x32_bf16(xh[rt].v, kl1.v, z1, 0, 0, 0);
                z1 = __builtin_amdgcn_mfma_f32_16x16x32_bf16(xh[rt].v, kh1.v, z1, 0, 0, 0);

                const int r0 = rbase + ((l >> 4) << 2);   // C layout: col=l&15, row=(l>>4)*4+r
                #pragma unroll
                for (int r = 0; r < 4; ++r) zS[r0 + r][n0] = z0[r];
                if (n0 < 4) {
                    #pragma unroll
                    for (int r = 0; r < 4; ++r) zS[r0 + r][16 + n0] = z1[r];
                }
            }
        }
    }
    __syncthreads();

    // ---- phase B epilogue: per-thread label-gathered softmax (fp32 exact) ----
    float a[SS];
    #pragma unroll
    for (int s = 0; s < SS; ++s) a[s] = 0.f;
    if (valid) {
        const int lab = (t < len - 1) ? labels[(size_t)b * TT + t] : 0;
        float z[SS];
        #pragma unroll
        for (int s = 0; s < SS; ++s) z[s] = zS[t][5 * lab + s];
        float m = z[0];
        #pragma unroll
        for (int s = 1; s < SS; ++s) m = fmaxf(m, z[s]);
        float e[SS];
        float sum = 0.f;
        #pragma unroll
        for (int s = 0; s < SS; ++s) { e[s] = __expf(z[s] - m); sum += e[s]; }
        const float inv = frcp(sum);
        #pragma unroll
        for (int s = 0; s < SS; ++s) a[s] = e[s] * inv;
    }

    // ---- phase C: suffix-product scan over t ----
    float excl[SS];
    if (wactive) {
        #pragma unroll
        for (int s = 0; s < SS; ++s) {
            float p = 1.f - a[s];
            #pragma unroll
            for (int off = 1; off < 64; off <<= 1) {
                const float o = __shfl_down(p, off);
                p = (l + off < 64) ? p * o : p;
            }
            float e = __shfl_down(p, 1);
            if (l == 63) e = 1.f;
            excl[s] = e;
            if (l == 0) wTot[w][s] = p;
        }
    } else {
        #pragma unroll
        for (int s = 0; s < SS; ++s) excl[s] = 1.f;
        if (l == 0) {
            #pragma unroll
            for (int s = 0; s < SS; ++s) wTot[w][s] = 1.f;
        }
    }

    // wave 0: r_attn = softmax_s(q . keys[ql][s]) straight from global
    if (w == 0) {
        const int d = l & (DD - 1);
        const float qv = q[(size_t)b * DD + d];
        float p[SS];
        #pragma unroll
        for (int s = 0; s < SS; ++s) p[s] = qv * keys[(size_t)(ql * SS + s) * DD + d];
        #pragma unroll
        for (int m = 16; m >= 1; m >>= 1) {
            #pragma unroll
            for (int s = 0; s < SS; ++s) p[s] += __shfl_xor(p[s], m);
        }
        float mm = p[0];
        #pragma unroll
        for (int s = 1; s < SS; ++s) mm = fmaxf(mm, p[s]);
        float e[SS];
        float sum = 0.f;
        #pragma unroll
        for (int s = 0; s < SS; ++s) { e[s] = __expf(p[s] - mm); sum += e[s]; }
        const float inv = frcp(sum);
        if (l == 0) {
            #pragma unroll
            for (int s = 0; s < SS; ++s) rS[s] = e[s] * inv;
        }
    }
    __syncthreads();

    // ---- per-row scalar weight c_t -> LDS ----
    float c = 0.f;
    if (valid) {
        #pragma unroll
        for (int s = 0; s < SS; ++s) {
            float wsuf = 1.f;
            if (w <= 2) wsuf *= wTot[3][s];
            if (w <= 1) wsuf *= wTot[2][s];
            if (w == 0) wsuf *= wTot[1][s];
            c += rS[s] * (a[s] * excl[s] * wsuf);
        }
    }
    cS[t] = c;
    __syncthreads();

    // ---- phase D: MFMA  U = sigmoid(X @ Wu + bu);  p = sum_t c_t * U_t ----
    float p0 = 0.f, p1 = 0.f;
    if (wactive) {
        F8 bw0, bw1;
        #pragma unroll
        for (int j = 0; j < 4; ++j) {
            const int k0 = kb + 2 * j;
            bw0.u[j] = f2bf2(Wu[k0 * DD + n0],      Wu[(k0 + 1) * DD + n0]);
            bw1.u[j] = f2bf2(Wu[k0 * DD + n0 + 16], Wu[(k0 + 1) * DD + n0 + 16]);
        }
        const float bub0 = bu[n0], bub1 = bu[n0 + 16];

        #pragma unroll
        for (int rt = 0; rt < 4; ++rt) {
            const int rbase = (w << 6) + (rt << 4);
            if (rbase < len) {                          // wave-uniform
                f32x4 acc0 = {0.f, 0.f, 0.f, 0.f};
                f32x4 acc1 = {0.f, 0.f, 0.f, 0.f};
                acc0 = __builtin_amdgcn_mfma_f32_16x16x32_bf16(xh[rt].v, bw0.v, acc0, 0, 0, 0);
                acc1 = __builtin_amdgcn_mfma_f32_16x16x32_bf16(xh[rt].v, bw1.v, acc1, 0, 0, 0);

                const float4 cf = *reinterpret_cast<const float4*>(&cS[rbase + ((l >> 4) << 2)]);
                const float cfa[4] = {cf.x, cf.y, cf.z, cf.w};
                #pragma unroll
                for (int r = 0; r < 4; ++r) {
                    p0 += cfa[r] * frcp(1.f + __expf(-(acc0[r] + bub0)));
                    p1 += cfa[r] * frcp(1.f + __expf(-(acc1[r] + bub1)));
                }
            }
        }
    }
    p0 += __shfl_xor(p0, 16); p0 += __shfl_xor(p0, 32);
    p1 += __shfl_xor(p1, 16); p1 += __shfl_xor(p1, 32);
    if (l < 16) { red[w][l] = p0; red[w][l + 16] = p1; }
    __syncthreads();

    if (tid < DD) {
        out[(size_t)b * DD + tid] = red[0][tid] + red[1][tid] + red[2][tid] + red[3][tid];
    }
}

extern "C" void kernel_launch(void* const* d_in, const int* in_sizes, int n_in,
                              void* d_out, int out_size, void* d_ws, size_t ws_size,
                              hipStream_t stream) {
    const float* x      = (const float*)d_in[0];
    const float* q      = (const float*)d_in[1];
    const float* keys   = (const float*)d_in[2];
    const float* Wu     = (const float*)d_in[3];
    const float* bu     = (const float*)d_in[4];
    const int*   lens   = (const int*)d_in[5];
    const int*   labels = (const int*)d_in[6];
    const int*   qlab   = (const int*)d_in[7];
    float* out = (float*)d_out;

    hipLaunchKernelGGL(mem_net_kernel, dim3(4096), dim3(256), 0, stream,
                       x, q, keys, Wu, bu, lens, labels, qlab, out);
}